// Round 1
// baseline (907.855 us; speedup 1.0000x reference)
//
#include <hip/hip_runtime.h>

#define N_IN   100000
#define N_OUT  400000
#define KK     8
#define PP     100000
#define C_IN   128
#define C_OUTC 64
#define C_SKIP 64
#define EPS_BN 1e-5f

// ---------------------------------------------------------------------------
// Scatter: y[out_idx] += x[in_idx] @ W_deconv[k]
// One wave handles 4 rulebook pairs per iteration; lane = output channel.
// PP % 4 == 0, so a group of 4 consecutive pairs never crosses a k boundary.
// ---------------------------------------------------------------------------
__global__ __launch_bounds__(256) void scatter_kernel(
    const float* __restrict__ x, const float* __restrict__ Wd,
    const int* __restrict__ in_idx, const int* __restrict__ out_idx,
    float* __restrict__ y)
{
    const int lane   = threadIdx.x & 63;
    const int wave   = (int)((blockIdx.x * blockDim.x + threadIdx.x) >> 6);
    const int nwaves = (int)((gridDim.x * blockDim.x) >> 6);
    const int ngroups = (KK * PP) / 4;   // 200000

    for (int g = wave; g < ngroups; g += nwaves) {
        const int q0 = g * 4;
        const int k  = q0 / PP;                       // uniform over the group
        const float* __restrict__ Wk = Wd + (size_t)k * (C_IN * C_OUTC);

        const int ip0 = __builtin_amdgcn_readfirstlane(in_idx[q0 + 0]);
        const int ip1 = __builtin_amdgcn_readfirstlane(in_idx[q0 + 1]);
        const int ip2 = __builtin_amdgcn_readfirstlane(in_idx[q0 + 2]);
        const int ip3 = __builtin_amdgcn_readfirstlane(in_idx[q0 + 3]);
        const int op0 = __builtin_amdgcn_readfirstlane(out_idx[q0 + 0]);
        const int op1 = __builtin_amdgcn_readfirstlane(out_idx[q0 + 1]);
        const int op2 = __builtin_amdgcn_readfirstlane(out_idx[q0 + 2]);
        const int op3 = __builtin_amdgcn_readfirstlane(out_idx[q0 + 3]);

        const float* __restrict__ x0 = x + (size_t)ip0 * C_IN;
        const float* __restrict__ x1 = x + (size_t)ip1 * C_IN;
        const float* __restrict__ x2 = x + (size_t)ip2 * C_IN;
        const float* __restrict__ x3 = x + (size_t)ip3 * C_IN;

        float a0 = 0.f, a1 = 0.f, a2 = 0.f, a3 = 0.f;
        #pragma unroll 16
        for (int i = 0; i < C_IN; ++i) {
            const float w = Wk[i * C_OUTC + lane];
            a0 += x0[i] * w;
            a1 += x1[i] * w;
            a2 += x2[i] * w;
            a3 += x3[i] * w;
        }
        atomicAdd(&y[(size_t)op0 * C_OUTC + lane], a0);
        atomicAdd(&y[(size_t)op1 * C_OUTC + lane], a1);
        atomicAdd(&y[(size_t)op2 * C_OUTC + lane], a2);
        atomicAdd(&y[(size_t)op3 * C_OUTC + lane], a3);
    }
}

// ---------------------------------------------------------------------------
// Per-channel sum and sum-of-squares over y  -> stats[0:64]=sum, [64:128]=sumsq
// ---------------------------------------------------------------------------
__global__ __launch_bounds__(256) void stats_kernel(
    const float* __restrict__ y, float* __restrict__ stats)
{
    const int c   = threadIdx.x & 63;
    const int grp = threadIdx.x >> 6;          // 0..3
    const int gid  = blockIdx.x * 4 + grp;
    const int ngrp = gridDim.x * 4;

    float s = 0.f, s2 = 0.f;
    for (int r = gid; r < N_OUT; r += ngrp) {
        const float v = y[(size_t)r * C_OUTC + c];
        s  += v;
        s2 += v * v;
    }
    __shared__ float ls[4][C_OUTC];
    __shared__ float ls2[4][C_OUTC];
    ls[grp][c]  = s;
    ls2[grp][c] = s2;
    __syncthreads();
    if (grp == 0) {
        s  = ls[0][c]  + ls[1][c]  + ls[2][c]  + ls[3][c];
        s2 = ls2[0][c] + ls2[1][c] + ls2[2][c] + ls2[3][c];
        atomicAdd(&stats[c], s);
        atomicAdd(&stats[C_OUTC + c], s2);
    }
}

// ---------------------------------------------------------------------------
// Fold gamma/beta/mean/var into per-channel scale & shift.
// ---------------------------------------------------------------------------
__global__ void finalize_kernel(const float* __restrict__ stats,
                                const float* __restrict__ gamma,
                                const float* __restrict__ beta,
                                float* __restrict__ sc)
{
    const int c = threadIdx.x;                 // 64 threads
    const float inv_n = 1.0f / (float)N_OUT;
    const float mean  = stats[c] * inv_n;
    const float var   = stats[C_OUTC + c] * inv_n - mean * mean;
    const float s     = gamma[c] * rsqrtf(var + EPS_BN);
    sc[c]          = s;
    sc[C_OUTC + c] = beta[c] - mean * s;
}

// ---------------------------------------------------------------------------
// In-place BN + ReLU on y (vectorized float4).
// ---------------------------------------------------------------------------
__global__ __launch_bounds__(256) void bnrelu_kernel(
    float* __restrict__ y, const float* __restrict__ sc)
{
    const size_t total4 = (size_t)N_OUT * C_OUTC / 4;   // 6.4M float4
    const size_t stride = (size_t)gridDim.x * blockDim.x;
    for (size_t i = blockIdx.x * (size_t)blockDim.x + threadIdx.x;
         i < total4; i += stride) {
        const int cb = (int)(i & 15);                   // float4 index in row
        const float4 v  = ((const float4*)y)[i];
        const float4 s4 = ((const float4*)sc)[cb];
        const float4 b4 = ((const float4*)sc)[16 + cb];
        float4 r;
        r.x = fmaxf(v.x * s4.x + b4.x, 0.f);
        r.y = fmaxf(v.y * s4.y + b4.y, 0.f);
        r.z = fmaxf(v.z * s4.z + b4.z, 0.f);
        r.w = fmaxf(v.w * s4.w + b4.w, 0.f);
        ((float4*)y)[i] = r;
    }
}

// ---------------------------------------------------------------------------
// Fused concat + linear:  out[n] = ybn[n] @ Wf[0:64] + skip[n] @ Wf[64:128]
// In-place on y: each wave reads its 4 rows fully before overwriting them.
// ---------------------------------------------------------------------------
__global__ __launch_bounds__(256) void fuse_kernel(
    float* __restrict__ y, const float* __restrict__ skip,
    const float* __restrict__ Wf)
{
    const int lane   = threadIdx.x & 63;
    const int wave   = (int)((blockIdx.x * blockDim.x + threadIdx.x) >> 6);
    const int nwaves = (int)((gridDim.x * blockDim.x) >> 6);
    const int ngroups = N_OUT / 4;   // 100000

    for (int g = wave; g < ngroups; g += nwaves) {
        const int r0 = g * 4;
        const float* __restrict__ yr = y    + (size_t)r0 * C_OUTC;
        const float* __restrict__ sr = skip + (size_t)r0 * C_SKIP;

        float a0 = 0.f, a1 = 0.f, a2 = 0.f, a3 = 0.f;
        #pragma unroll 16
        for (int i = 0; i < C_OUTC; ++i) {
            const float w = Wf[i * C_OUTC + lane];
            a0 += yr[i]       * w;
            a1 += yr[64 + i]  * w;
            a2 += yr[128 + i] * w;
            a3 += yr[192 + i] * w;
        }
        #pragma unroll 16
        for (int i = 0; i < C_SKIP; ++i) {
            const float w = Wf[(C_OUTC + i) * C_OUTC + lane];
            a0 += sr[i]       * w;
            a1 += sr[64 + i]  * w;
            a2 += sr[128 + i] * w;
            a3 += sr[192 + i] * w;
        }
        y[(size_t)(r0 + 0) * C_OUTC + lane] = a0;
        y[(size_t)(r0 + 1) * C_OUTC + lane] = a1;
        y[(size_t)(r0 + 2) * C_OUTC + lane] = a2;
        y[(size_t)(r0 + 3) * C_OUTC + lane] = a3;
    }
}

// ---------------------------------------------------------------------------
extern "C" void kernel_launch(void* const* d_in, const int* in_sizes, int n_in,
                              void* d_out, int out_size, void* d_ws, size_t ws_size,
                              hipStream_t stream)
{
    const float* x      = (const float*)d_in[0];
    const float* skip   = (const float*)d_in[1];
    const float* Wd     = (const float*)d_in[2];
    const float* gamma  = (const float*)d_in[3];
    const float* beta   = (const float*)d_in[4];
    const float* Wf     = (const float*)d_in[5];
    const int*   in_idx  = (const int*)d_in[6];
    const int*   out_idx = (const int*)d_in[7];

    float* y     = (float*)d_out;            // y lives in d_out (same shape)
    float* stats = (float*)d_ws;             // 128 floats: sum | sumsq
    float* sc    = stats + 128;              // 128 floats: scale | shift

    hipMemsetAsync(d_out, 0, (size_t)N_OUT * C_OUTC * sizeof(float), stream);
    hipMemsetAsync(d_ws, 0, 128 * sizeof(float), stream);

    scatter_kernel<<<2048, 256, 0, stream>>>(x, Wd, in_idx, out_idx, y);
    stats_kernel<<<1024, 256, 0, stream>>>(y, stats);
    finalize_kernel<<<1, 64, 0, stream>>>(stats, gamma, beta, sc);
    bnrelu_kernel<<<2048, 256, 0, stream>>>(y, sc);
    fuse_kernel<<<2048, 256, 0, stream>>>(y, skip, Wf);
}

// Round 2
// 803.348 us; speedup vs baseline: 1.1301x; 1.1301x over previous
//
#include <hip/hip_runtime.h>

#define N_IN   100000
#define N_OUT  400000
#define KK     8
#define PP     100000
#define C_IN   128
#define C_OUTC 64
#define C_SKIP 64
#define EPS_BN 1e-5f

// ---------------------------------------------------------------------------
// Scatter: y[out_idx] += x[in_idx] @ W_deconv[k]
// blockIdx.y = k. Wk staged in LDS (32 KB). 8 pairs per wave-iteration:
// weight ds_read amortized 8x; row data via scalar loads (uniform bases).
// ---------------------------------------------------------------------------
__global__ __launch_bounds__(512) void scatter_kernel(
    const float* __restrict__ x, const float* __restrict__ Wd,
    const int* __restrict__ in_idx, const int* __restrict__ out_idx,
    float* __restrict__ y)
{
    __shared__ float wlds[C_IN * C_OUTC];          // 32 KB
    const int k = blockIdx.y;
    {
        const float4* src = (const float4*)(Wd + (size_t)k * (C_IN * C_OUTC));
        for (int t = threadIdx.x; t < (C_IN * C_OUTC) / 4; t += 512)
            ((float4*)wlds)[t] = src[t];
    }
    __syncthreads();

    const int lane = threadIdx.x & 63;
    int wv = (int)((blockIdx.x * 512 + threadIdx.x) >> 6);
    wv = __builtin_amdgcn_readfirstlane(wv);       // force SGPR wave id
    const int nw = gridDim.x * 8;
    const int* __restrict__ ii = in_idx + k * PP;
    const int* __restrict__ oi = out_idx + k * PP;

    for (int g = wv; g < PP / 8; g += nw) {
        const int q0 = g * 8;
        int ip[8], op[8];
        #pragma unroll
        for (int j = 0; j < 8; ++j) { ip[j] = ii[q0 + j]; op[j] = oi[q0 + j]; }

        float acc[8] = {0.f,0.f,0.f,0.f,0.f,0.f,0.f,0.f};
        #pragma unroll 8
        for (int i = 0; i < C_IN; ++i) {
            const float w = wlds[i * C_OUTC + lane];          // ds_read, conflict-free
            #pragma unroll
            for (int j = 0; j < 8; ++j)
                acc[j] += x[(size_t)ip[j] * C_IN + i] * w;    // s_load row data
        }
        #pragma unroll
        for (int j = 0; j < 8; ++j)
            atomicAdd(&y[(size_t)op[j] * C_OUTC + lane], acc[j]);
    }
}

// ---------------------------------------------------------------------------
// Per-channel sum / sum-of-squares over y -> stats[0:64]=sum, [64:128]=sumsq
// ---------------------------------------------------------------------------
__global__ __launch_bounds__(256) void stats_kernel(
    const float* __restrict__ y, float* __restrict__ stats)
{
    const int c   = threadIdx.x & 63;
    const int grp = threadIdx.x >> 6;          // 0..3
    const int gid  = blockIdx.x * 4 + grp;
    const int ngrp = gridDim.x * 4;

    float s = 0.f, s2 = 0.f;
    for (int r = gid; r < N_OUT; r += ngrp) {
        const float v = y[(size_t)r * C_OUTC + c];
        s  += v;
        s2 += v * v;
    }
    __shared__ float ls[4][C_OUTC];
    __shared__ float ls2[4][C_OUTC];
    ls[grp][c]  = s;
    ls2[grp][c] = s2;
    __syncthreads();
    if (grp == 0) {
        s  = ls[0][c]  + ls[1][c]  + ls[2][c]  + ls[3][c];
        s2 = ls2[0][c] + ls2[1][c] + ls2[2][c] + ls2[3][c];
        atomicAdd(&stats[c], s);
        atomicAdd(&stats[C_OUTC + c], s2);
    }
}

// ---------------------------------------------------------------------------
// Fold gamma/beta/mean/var into per-channel scale & shift.
// ---------------------------------------------------------------------------
__global__ void finalize_kernel(const float* __restrict__ stats,
                                const float* __restrict__ gamma,
                                const float* __restrict__ beta,
                                float* __restrict__ sc)
{
    const int c = threadIdx.x;                 // 64 threads
    const float inv_n = 1.0f / (float)N_OUT;
    const float mean  = stats[c] * inv_n;
    const float var   = stats[C_OUTC + c] * inv_n - mean * mean;
    const float s     = gamma[c] * rsqrtf(var + EPS_BN);
    sc[c]          = s;
    sc[C_OUTC + c] = beta[c] - mean * s;
}

// ---------------------------------------------------------------------------
// In-place BN + ReLU on y (vectorized float4).
// ---------------------------------------------------------------------------
__global__ __launch_bounds__(256) void bnrelu_kernel(
    float* __restrict__ y, const float* __restrict__ sc)
{
    const size_t total4 = (size_t)N_OUT * C_OUTC / 4;   // 6.4M float4
    const size_t stride = (size_t)gridDim.x * blockDim.x;
    for (size_t i = blockIdx.x * (size_t)blockDim.x + threadIdx.x;
         i < total4; i += stride) {
        const int cb = (int)(i & 15);                   // float4 index in row
        const float4 v  = ((const float4*)y)[i];
        const float4 s4 = ((const float4*)sc)[cb];
        const float4 b4 = ((const float4*)sc)[16 + cb];
        float4 r;
        r.x = fmaxf(v.x * s4.x + b4.x, 0.f);
        r.y = fmaxf(v.y * s4.y + b4.y, 0.f);
        r.z = fmaxf(v.z * s4.z + b4.z, 0.f);
        r.w = fmaxf(v.w * s4.w + b4.w, 0.f);
        ((float4*)y)[i] = r;
    }
}

// ---------------------------------------------------------------------------
// Fused concat + linear: out[n] = ybn[n] @ Wf[0:64] + skip[n] @ Wf[64:128]
// Wf staged in LDS; 8 rows per wave-iteration; rows via scalar loads.
// In-place on y: each wave reads its 8 rows fully before overwriting them.
// ---------------------------------------------------------------------------
__global__ __launch_bounds__(512) void fuse_kernel(
    float* __restrict__ y, const float* __restrict__ skip,
    const float* __restrict__ Wf)
{
    __shared__ float wlds[(C_OUTC + C_SKIP) * C_OUTC];   // 32 KB
    for (int t = threadIdx.x; t < ((C_OUTC + C_SKIP) * C_OUTC) / 4; t += 512)
        ((float4*)wlds)[t] = ((const float4*)Wf)[t];
    __syncthreads();

    const int lane = threadIdx.x & 63;
    int wv = (int)((blockIdx.x * 512 + threadIdx.x) >> 6);
    wv = __builtin_amdgcn_readfirstlane(wv);
    const int nw = gridDim.x * 8;

    for (int g = wv; g < N_OUT / 8; g += nw) {
        const float* __restrict__ yr = y    + (size_t)g * 8 * C_OUTC;
        const float* __restrict__ sr = skip + (size_t)g * 8 * C_SKIP;

        float acc[8] = {0.f,0.f,0.f,0.f,0.f,0.f,0.f,0.f};
        #pragma unroll 8
        for (int i = 0; i < C_OUTC; ++i) {
            const float w = wlds[i * C_OUTC + lane];
            #pragma unroll
            for (int r = 0; r < 8; ++r)
                acc[r] += yr[r * C_OUTC + i] * w;
        }
        #pragma unroll 8
        for (int i = 0; i < C_SKIP; ++i) {
            const float w = wlds[(C_OUTC + i) * C_OUTC + lane];
            #pragma unroll
            for (int r = 0; r < 8; ++r)
                acc[r] += sr[r * C_SKIP + i] * w;
        }
        #pragma unroll
        for (int r = 0; r < 8; ++r)
            y[((size_t)g * 8 + r) * C_OUTC + lane] = acc[r];
    }
}

// ---------------------------------------------------------------------------
extern "C" void kernel_launch(void* const* d_in, const int* in_sizes, int n_in,
                              void* d_out, int out_size, void* d_ws, size_t ws_size,
                              hipStream_t stream)
{
    const float* x      = (const float*)d_in[0];
    const float* skip   = (const float*)d_in[1];
    const float* Wd     = (const float*)d_in[2];
    const float* gamma  = (const float*)d_in[3];
    const float* beta   = (const float*)d_in[4];
    const float* Wf     = (const float*)d_in[5];
    const int*   in_idx  = (const int*)d_in[6];
    const int*   out_idx = (const int*)d_in[7];

    float* y     = (float*)d_out;            // y lives in d_out (same shape)
    float* stats = (float*)d_ws;             // 128 floats: sum | sumsq
    float* sc    = stats + 128;              // 128 floats: scale | shift

    hipMemsetAsync(d_out, 0, (size_t)N_OUT * C_OUTC * sizeof(float), stream);
    hipMemsetAsync(d_ws, 0, 128 * sizeof(float), stream);

    dim3 sgrid(128, KK, 1);                  // 1024 blocks, blockIdx.y = k
    scatter_kernel<<<sgrid, 512, 0, stream>>>(x, Wd, in_idx, out_idx, y);
    stats_kernel<<<2048, 256, 0, stream>>>(y, stats);
    finalize_kernel<<<1, 64, 0, stream>>>(stats, gamma, beta, sc);
    bnrelu_kernel<<<2048, 256, 0, stream>>>(y, sc);
    fuse_kernel<<<1024, 512, 0, stream>>>(y, skip, Wf);
}